// Round 7
// baseline (125.149 us; speedup 1.0000x reference)
//
#include <hip/hip_runtime.h>

// Problem constants: B=4, S=512, H=256
#define Bn 4
#define Sn 512
#define Hn 256

#define CC   2.8853900817779268f   // 2*log2(e)
#define L2E  1.4426950408889634f

typedef __attribute__((ext_vector_type(4))) float f32x4;
typedef __attribute__((ext_vector_type(8))) short short8;

__device__ __forceinline__ unsigned short bf16rn(float f) {
    unsigned int u = __float_as_uint(f);
    u += 0x7fffu + ((u >> 16) & 1u);
    return (unsigned short)(u >> 16);
}
__device__ __forceinline__ float bf16tof(unsigned short b) {
    return __uint_as_float(((unsigned int)b) << 16);
}

// ---------------------------------------------------------------------------
// prep: merged splitA (h -> h1,h2 bf16 planes; 256 blocks) and splitB
// (Wt/Wp -> transposed bf16 split planes; 32 blocks). 288 blocks x 256 thr.
// ---------------------------------------------------------------------------
__global__ __launch_bounds__(256) void prep_kernel(
    const float* __restrict__ h,  const float* __restrict__ Wt,
    const float* __restrict__ Wp, const float* __restrict__ Wa,
    const float* __restrict__ ba,
    unsigned short* __restrict__ h1, unsigned short* __restrict__ h2,
    unsigned short* __restrict__ wtp,
    float* __restrict__ wa2, float* __restrict__ cst)
{
    __shared__ float tile[64 * 68];   // splitB transpose buffer
    __shared__ float red4[4];
    const int tid = threadIdx.x;
    const int bid = blockIdx.x;

    if (bid < 256) {
        // ---- splitA ----
        const int base = (bid * 256 + tid) * 8;
        float4 v0 = *(const float4*)&h[base];
        float4 v1 = *(const float4*)&h[base + 4];
        float f[8] = {v0.x, v0.y, v0.z, v0.w, v1.x, v1.y, v1.z, v1.w};
        unsigned short b1[8], b2[8];
#pragma unroll
        for (int i = 0; i < 8; i++) {
            b1[i] = bf16rn(f[i]);
            b2[i] = bf16rn(f[i] - bf16tof(b1[i]));
        }
        uint4 u1, u2;
        u1.x = (unsigned)b1[0] | ((unsigned)b1[1] << 16);
        u1.y = (unsigned)b1[2] | ((unsigned)b1[3] << 16);
        u1.z = (unsigned)b1[4] | ((unsigned)b1[5] << 16);
        u1.w = (unsigned)b1[6] | ((unsigned)b1[7] << 16);
        u2.x = (unsigned)b2[0] | ((unsigned)b2[1] << 16);
        u2.y = (unsigned)b2[2] | ((unsigned)b2[3] << 16);
        u2.z = (unsigned)b2[4] | ((unsigned)b2[5] << 16);
        u2.w = (unsigned)b2[6] | ((unsigned)b2[7] << 16);
        *(uint4*)&h1[base] = u1;
        *(uint4*)&h2[base] = u2;

        if (bid == 0) {
            float w = Wa[tid];
#pragma unroll
            for (int off = 32; off >= 1; off >>= 1) w += __shfl_xor(w, off, 64);
            if ((tid & 63) == 0) red4[tid >> 6] = w;
            __syncthreads();
            wa2[tid] = -2.0f * Wa[tid];
            if (tid == 0)
                cst[0] = -L2E * ((red4[0] + red4[1] + red4[2] + red4[3]) + ba[0]);
        }
    } else {
        // ---- splitB ----
        const int sb  = bid - 256;
        const int mat = sb >> 4;
        const int t4  = sb & 15;
        const int k0  = (t4 >> 2) * 64, n0 = (t4 & 3) * 64;
        const float* __restrict__ W = mat ? Wp : Wt;

#pragma unroll
        for (int i = 0; i < 4; i++) {
            const int idx = tid + 256 * i;
            const int kr = idx >> 4, nq = idx & 15;
            *(float4*)&tile[kr * 68 + nq * 4] =
                *(const float4*)&W[(k0 + kr) * Hn + n0 + nq * 4];
        }
        __syncthreads();

        unsigned short* p1 = wtp + mat * 2 * 65536;
        unsigned short* p2 = p1 + 65536;
#pragma unroll
        for (int i = 0; i < 8; i++) {
            const int idx = tid + 256 * i;
            const int n = idx >> 5, kp = idx & 31;
            const float f0 = tile[(2 * kp) * 68 + n];
            const float f1 = tile[(2 * kp + 1) * 68 + n];
            const unsigned short a0 = bf16rn(f0), a1 = bf16rn(f1);
            const unsigned short c0 = bf16rn(f0 - bf16tof(a0));
            const unsigned short c1 = bf16rn(f1 - bf16tof(a1));
            const int dw = ((n0 + n) * 256 + k0) / 2 + kp;
            ((unsigned int*)p1)[dw] = (unsigned)a0 | ((unsigned)a1 << 16);
            ((unsigned int*)p2)[dw] = (unsigned)c0 | ((unsigned)c1 << 16);
        }
    }
}

// ---------------------------------------------------------------------------
// gemm: C[2048][512] = h @ [Wt|Wp] via 16x16x32 bf16 MFMA, split-precision
// (a1w1 + a1w2 + a2w1). Fused exp2 epilogue -> Egt (row-major, +bias) and
// Egp4 ([b][k4][s][4] interleaved). 256 blocks x 256 thr.
// ---------------------------------------------------------------------------
__global__ __launch_bounds__(256) void gemm_kernel(
    const unsigned short* __restrict__ h1, const unsigned short* __restrict__ h2,
    const unsigned short* __restrict__ wtp, const float* __restrict__ bh,
    float* __restrict__ Egt, float* __restrict__ Egp4)
{
    __shared__ char lds[20480];   // A1,A2,B1,B2 sections of 64 x 80 B

    const int tid = threadIdx.x;
    const int mb = blockIdx.x >> 3;
    const int nb = blockIdx.x & 7;
    const int m0 = mb * 64;
    const bool isT = (nb < 4);
    const int n0l = isT ? nb * 64 : (nb - 4) * 64;
    const unsigned short* pB1 = wtp + (isT ? 0 : 2 * 65536);
    const unsigned short* pB2 = pB1 + 65536;

    const int w    = tid >> 6;
    const int lane = tid & 63;
    const int quad = lane >> 4;
    const int l15  = lane & 15;

    f32x4 acc[4];
#pragma unroll
    for (int i = 0; i < 4; i++) acc[i] = (f32x4){0.f, 0.f, 0.f, 0.f};

    const int ssel = tid >> 7;
    const int spl  = (tid >> 6) & 1;
    const int srow = (tid & 63) >> 2;
    const int sseg = tid & 3;
    const unsigned short* gsrc =
        (ssel == 0) ? (spl ? h2 : h1) : (spl ? pB2 : pB1);
    const int growbase = (ssel == 0) ? m0 : n0l;
    char* ldsdst = lds + (ssel * 2 + spl) * 5120;

    for (int ks = 0; ks < 256; ks += 32) {
        __syncthreads();
#pragma unroll
        for (int i = 0; i < 4; i++) {
            const int row = srow + i * 16;
            uint4 v = *(const uint4*)&gsrc[(growbase + row) * 256 + ks + sseg * 8];
            *(uint4*)(ldsdst + row * 80 + sseg * 16) = v;
        }
        __syncthreads();

        const char* Ab = lds;
        const char* Bb = lds + 10240;
        const short8 b1 = *(const short8*)(Bb + (w * 16 + l15) * 80 + quad * 16);
        const short8 b2 = *(const short8*)(Bb + 5120 + (w * 16 + l15) * 80 + quad * 16);
#pragma unroll
        for (int mt = 0; mt < 4; mt++) {
            const short8 a1 = *(const short8*)(Ab + (mt * 16 + l15) * 80 + quad * 16);
            const short8 a2 = *(const short8*)(Ab + 5120 + (mt * 16 + l15) * 80 + quad * 16);
            acc[mt] = __builtin_amdgcn_mfma_f32_16x16x32_bf16(a1, b1, acc[mt], 0, 0, 0);
            acc[mt] = __builtin_amdgcn_mfma_f32_16x16x32_bf16(a1, b2, acc[mt], 0, 0, 0);
            acc[mt] = __builtin_amdgcn_mfma_f32_16x16x32_bf16(a2, b1, acc[mt], 0, 0, 0);
        }
    }

    __syncthreads();
    float* ct = (float*)lds;   // 64 x 68 floats
#pragma unroll
    for (int mt = 0; mt < 4; mt++)
#pragma unroll
        for (int r = 0; r < 4; r++)
            ct[(mt * 16 + quad * 4 + r) * 68 + w * 16 + l15] = acc[mt][r];
    __syncthreads();

    const int b  = m0 >> 9;
    const int s0 = m0 & 511;
    if (isT) {
        const int n0g = nb * 64;
#pragma unroll
        for (int i = 0; i < 4; i++) {
            const int item = tid + i * 256;
            const int mr = item >> 4, nq = item & 15;
            const float4 c  = *(const float4*)&ct[mr * 68 + nq * 4];
            const float4 bv = *(const float4*)&bh[n0g + nq * 4];
            float4 o;
            o.x = __builtin_amdgcn_exp2f((c.x + bv.x) * CC);
            o.y = __builtin_amdgcn_exp2f((c.y + bv.y) * CC);
            o.z = __builtin_amdgcn_exp2f((c.z + bv.z) * CC);
            o.w = __builtin_amdgcn_exp2f((c.w + bv.w) * CC);
            *(float4*)&Egt[(m0 + mr) * Hn + n0g + nq * 4] = o;
        }
    } else {
        const int kq0 = (nb - 4) * 16;
#pragma unroll
        for (int i = 0; i < 4; i++) {
            const int item = tid + i * 256;
            const int mr = item & 63, nq = item >> 6;
            const float4 c = *(const float4*)&ct[mr * 68 + nq * 4];
            float4 o;
            o.x = __builtin_amdgcn_exp2f(c.x * CC);
            o.y = __builtin_amdgcn_exp2f(c.y * CC);
            o.z = __builtin_amdgcn_exp2f(c.z * CC);
            o.w = __builtin_amdgcn_exp2f(c.w * CC);
            *(float4*)&Egp4[b * 131072 + (kq0 + nq) * 2048 + (s0 + mr) * 4] = o;
        }
    }
}

// ---------------------------------------------------------------------------
// attn: fused score + softmax + output matvec. 8 t-rows per block.
// Phase 1 (thread = t' column): 4-way-rcp factorized tanh, sigmoid, softmax;
//   attn row -> LDS + global. Phase 2 (thread = (c4, q-octant)): out = attn@h
//   with attn broadcast ds_reads. Grid 256 x 512 thr.
// ---------------------------------------------------------------------------
__global__ __launch_bounds__(512) void attn_kernel(
    const float* __restrict__ hsrc, const float* __restrict__ Egt,
    const float* __restrict__ Egp4, const float* __restrict__ wa2,
    const float* __restrict__ cst,
    float* __restrict__ out, float* __restrict__ out_attn)
{
    // Aliased LDS: phase1 egt8[2048] (0..8K) | wal (16K..17K) | red (17K..17.25K)
    //              phase2 attn_l[8][512] (0..16K) | part 32KB (16K..48K)
    __shared__ char smem[49152];
    float*  egt8   = (float*)smem;
    float*  attn_l = (float*)smem;
    float*  wal    = (float*)(smem + 16384);
    float*  red    = (float*)(smem + 17408);
    float4* part   = (float4*)(smem + 16384);

    const int tid = threadIdx.x;
    const int b   = blockIdx.x & 3;
    const int t0  = (blockIdx.x >> 2) << 3;

    for (int i = tid; i < 8 * Hn; i += 512)
        egt8[i] = Egt[(b * Sn + t0) * Hn + i];
    if (tid < 256) wal[tid] = wa2[tid];
    __syncthreads();

    const float4* __restrict__ ep = (const float4*)(Egp4 + b * (Hn * Sn));

    float acc[8];
#pragma unroll
    for (int r = 0; r < 8; r++) acc[r] = 0.f;

    float4 cur = ep[tid];
    float4 nxt = ep[Sn + tid];
    for (int k4 = 0; k4 < 64; k4++) {
        const float4 nn = ep[((k4 + 2) & 63) * Sn + tid];   // wraps: tail reads k4=0,1 (unused)
        const float4 w4 = *(const float4*)&wal[k4 * 4];
#pragma unroll
        for (int r = 0; r < 8; r++) {
            const float4 eg = *(const float4*)&egt8[r * Hn + k4 * 4];  // broadcast
            const float d1 = fmaf(cur.x, eg.x, 1.0f);
            const float d2 = fmaf(cur.y, eg.y, 1.0f);
            const float d3 = fmaf(cur.z, eg.z, 1.0f);
            const float d4 = fmaf(cur.w, eg.w, 1.0f);
            const float p12 = d1 * d2, p34 = d3 * d4;
            const float n12 = fmaf(w4.x, d2, w4.y * d1);
            const float n34 = fmaf(w4.z, d4, w4.w * d3);
            const float num = fmaf(n12, p34, n34 * p12);
            acc[r] = fmaf(num, __builtin_amdgcn_rcpf(p12 * p34), acc[r]);
        }
        cur = nxt; nxt = nn;
    }

    // sigmoid of score, then exp for softmax (sig in (0,1): no max-sub)
    const float k0 = cst[0];
    float ex[8];
#pragma unroll
    for (int r = 0; r < 8; r++) {
        const float e1  = __builtin_amdgcn_exp2f(fmaf(-L2E, acc[r], k0));
        const float sig = __builtin_amdgcn_rcpf(1.0f + e1);
        ex[r] = __builtin_amdgcn_exp2f(L2E * sig);
    }

    const int lane = tid & 63, wid = tid >> 6;
#pragma unroll
    for (int r = 0; r < 8; r++) {
        float v = ex[r];
#pragma unroll
        for (int off = 32; off >= 1; off >>= 1) v += __shfl_xor(v, off, 64);
        if (lane == 0) red[r * 8 + wid] = v;
    }
    __syncthreads();   // all threads past k4 loop (egt8 dead) and red written

#pragma unroll
    for (int r = 0; r < 8; r++) {
        float tot = 0.f;
#pragma unroll
        for (int i = 0; i < 8; i++) tot += red[r * 8 + i];
        const float a = ex[r] * __builtin_amdgcn_rcpf(tot);
        attn_l[r * Sn + tid] = a;                       // aliases egt8 (dead)
        out_attn[(b * Sn + t0 + r) * Sn + tid] = a;
    }
    __syncthreads();

    // ---- phase 2: out rows = attn @ h ----
    const int c4 = tid & 63;
    const int q  = __builtin_amdgcn_readfirstlane(tid >> 6);   // 0..7, wave-uniform

    const float* __restrict__ hb = hsrc + (b * Sn + q * 64) * Hn + c4 * 4;

    float4 a[8];
#pragma unroll
    for (int r = 0; r < 8; r++) a[r] = (float4){0.f, 0.f, 0.f, 0.f};

#pragma unroll 2
    for (int j4 = 0; j4 < 16; j4++) {
        float4 wv[8];
#pragma unroll
        for (int r = 0; r < 8; r++)
            wv[r] = *(const float4*)&attn_l[r * Sn + q * 64 + j4 * 4];  // broadcast
#pragma unroll
        for (int i = 0; i < 4; i++) {
            const float4 hv = *(const float4*)&hb[(j4 * 4 + i) * Hn];
#pragma unroll
            for (int r = 0; r < 8; r++) {
                const float wr = ((const float*)&wv[r])[i];
                a[r].x = fmaf(wr, hv.x, a[r].x);
                a[r].y = fmaf(wr, hv.y, a[r].y);
                a[r].z = fmaf(wr, hv.z, a[r].z);
                a[r].w = fmaf(wr, hv.w, a[r].w);
            }
        }
    }
    __syncthreads();   // attn_l reads done before part (16K..48K) overwrites red zone

    if (q < 4) {
#pragma unroll
        for (int r = 0; r < 8; r++) part[(q * 8 + r) * 64 + c4] = a[r];
    }
    __syncthreads();
    if (q >= 4) {
#pragma unroll
        for (int r = 0; r < 8; r++) {
            float4 p = part[((q - 4) * 8 + r) * 64 + c4];
            p.x += a[r].x; p.y += a[r].y; p.z += a[r].z; p.w += a[r].w;
            part[((q - 4) * 8 + r) * 64 + c4] = p;
        }
    }
    __syncthreads();

    const int col = tid & 255;
    const int rs  = tid >> 8;
    const float* pf = (const float*)part;
#pragma unroll
    for (int rr = 0; rr < 4; rr++) {
        const int r = rs * 4 + rr;
        float s = 0.f;
#pragma unroll
        for (int qq = 0; qq < 4; qq++)
            s += pf[((qq * 8 + r) * 64 + (col >> 2)) * 4 + (col & 3)];
        out[(b * Sn + t0 + r) * Hn + col] = s;
    }
}

extern "C" void kernel_launch(void* const* d_in, const int* in_sizes, int n_in,
                              void* d_out, int out_size, void* d_ws, size_t ws_size,
                              hipStream_t stream) {
    const float* h   = (const float*)d_in[0];
    const float* Wt  = (const float*)d_in[1];
    const float* Wtp = (const float*)d_in[2];
    const float* bh  = (const float*)d_in[3];
    const float* Wa  = (const float*)d_in[4];
    const float* ba  = (const float*)d_in[5];

    float* out      = (float*)d_out;                 // (B,S,H) = 524288
    float* out_attn = out + Bn * Sn * Hn;            // (B,S,S) = 1048576

    float* ws   = (float*)d_ws;
    float* Egt  = ws;                                 // 524288 f
    float* Egp4 = ws + 524288;                        // 524288 f
    float* wa2  = ws + 1048576;                       // 256 f
    float* cst  = ws + 1048832;                       // 1 f
    unsigned short* h1  = (unsigned short*)(ws + 1048840);   // 524288 us
    unsigned short* h2  = h1 + 2048 * 256;                   // 524288 us
    unsigned short* wtp = h2 + 2048 * 256;                   // 4 x 65536 us

    prep_kernel<<<dim3(288), dim3(256), 0, stream>>>(
        h, Wt, Wtp, Wa, ba, h1, h2, wtp, wa2, cst);
    gemm_kernel<<<dim3(256), dim3(256), 0, stream>>>(h1, h2, wtp, bh, Egt, Egp4);
    attn_kernel<<<dim3(Bn * (Sn / 8)), dim3(512), 0, stream>>>(
        h, Egt, Egp4, wa2, cst, out, out_attn);
}

// Round 8
// 124.197 us; speedup vs baseline: 1.0077x; 1.0077x over previous
//
#include <hip/hip_runtime.h>

// Problem constants: B=4, S=512, H=256
#define Bn 4
#define Sn 512
#define Hn 256

#define CC   2.8853900817779268f   // 2*log2(e)
#define L2E  1.4426950408889634f

typedef __attribute__((ext_vector_type(4))) float f32x4;
typedef __attribute__((ext_vector_type(2))) float f32x2;
typedef __attribute__((ext_vector_type(8))) short short8;

__device__ __forceinline__ unsigned short bf16rn(float f) {
    unsigned int u = __float_as_uint(f);
    u += 0x7fffu + ((u >> 16) & 1u);
    return (unsigned short)(u >> 16);
}
__device__ __forceinline__ float bf16tof(unsigned short b) {
    return __uint_as_float(((unsigned int)b) << 16);
}

// ---------------------------------------------------------------------------
// prep: merged splitA (h -> h1,h2 bf16 planes; 256 blocks) and splitB
// (Wt/Wp -> transposed bf16 split planes; 32 blocks). 288 blocks x 256 thr.
// ---------------------------------------------------------------------------
__global__ __launch_bounds__(256) void prep_kernel(
    const float* __restrict__ h,  const float* __restrict__ Wt,
    const float* __restrict__ Wp, const float* __restrict__ Wa,
    const float* __restrict__ ba,
    unsigned short* __restrict__ h1, unsigned short* __restrict__ h2,
    unsigned short* __restrict__ wtp,
    float* __restrict__ wa2, float* __restrict__ cst)
{
    __shared__ float tile[64 * 68];
    __shared__ float red4[4];
    const int tid = threadIdx.x;
    const int bid = blockIdx.x;

    if (bid < 256) {
        const int base = (bid * 256 + tid) * 8;
        float4 v0 = *(const float4*)&h[base];
        float4 v1 = *(const float4*)&h[base + 4];
        float f[8] = {v0.x, v0.y, v0.z, v0.w, v1.x, v1.y, v1.z, v1.w};
        unsigned short b1[8], b2[8];
#pragma unroll
        for (int i = 0; i < 8; i++) {
            b1[i] = bf16rn(f[i]);
            b2[i] = bf16rn(f[i] - bf16tof(b1[i]));
        }
        uint4 u1, u2;
        u1.x = (unsigned)b1[0] | ((unsigned)b1[1] << 16);
        u1.y = (unsigned)b1[2] | ((unsigned)b1[3] << 16);
        u1.z = (unsigned)b1[4] | ((unsigned)b1[5] << 16);
        u1.w = (unsigned)b1[6] | ((unsigned)b1[7] << 16);
        u2.x = (unsigned)b2[0] | ((unsigned)b2[1] << 16);
        u2.y = (unsigned)b2[2] | ((unsigned)b2[3] << 16);
        u2.z = (unsigned)b2[4] | ((unsigned)b2[5] << 16);
        u2.w = (unsigned)b2[6] | ((unsigned)b2[7] << 16);
        *(uint4*)&h1[base] = u1;
        *(uint4*)&h2[base] = u2;

        if (bid == 0) {
            float w = Wa[tid];
#pragma unroll
            for (int off = 32; off >= 1; off >>= 1) w += __shfl_xor(w, off, 64);
            if ((tid & 63) == 0) red4[tid >> 6] = w;
            __syncthreads();
            wa2[tid] = -2.0f * Wa[tid];
            if (tid == 0)
                cst[0] = -L2E * ((red4[0] + red4[1] + red4[2] + red4[3]) + ba[0]);
        }
    } else {
        const int sb  = bid - 256;
        const int mat = sb >> 4;
        const int t4  = sb & 15;
        const int k0  = (t4 >> 2) * 64, n0 = (t4 & 3) * 64;
        const float* __restrict__ W = mat ? Wp : Wt;

#pragma unroll
        for (int i = 0; i < 4; i++) {
            const int idx = tid + 256 * i;
            const int kr = idx >> 4, nq = idx & 15;
            *(float4*)&tile[kr * 68 + nq * 4] =
                *(const float4*)&W[(k0 + kr) * Hn + n0 + nq * 4];
        }
        __syncthreads();

        unsigned short* p1 = wtp + mat * 2 * 65536;
        unsigned short* p2 = p1 + 65536;
#pragma unroll
        for (int i = 0; i < 8; i++) {
            const int idx = tid + 256 * i;
            const int n = idx >> 5, kp = idx & 31;
            const float f0 = tile[(2 * kp) * 68 + n];
            const float f1 = tile[(2 * kp + 1) * 68 + n];
            const unsigned short a0 = bf16rn(f0), a1 = bf16rn(f1);
            const unsigned short c0 = bf16rn(f0 - bf16tof(a0));
            const unsigned short c1 = bf16rn(f1 - bf16tof(a1));
            const int dw = ((n0 + n) * 256 + k0) / 2 + kp;
            ((unsigned int*)p1)[dw] = (unsigned)a0 | ((unsigned)a1 << 16);
            ((unsigned int*)p2)[dw] = (unsigned)c0 | ((unsigned)c1 << 16);
        }
    }
}

// ---------------------------------------------------------------------------
// gemm: C[2048][512] = h @ [Wt|Wp] via 16x16x32 bf16 MFMA, split-precision
// (a1w1 + a1w2 + a2w1). Fused exp2 epilogue -> Egt / Egp4. 256 blk x 256 thr.
// ---------------------------------------------------------------------------
__global__ __launch_bounds__(256) void gemm_kernel(
    const unsigned short* __restrict__ h1, const unsigned short* __restrict__ h2,
    const unsigned short* __restrict__ wtp, const float* __restrict__ bh,
    float* __restrict__ Egt, float* __restrict__ Egp4)
{
    __shared__ char lds[20480];

    const int tid = threadIdx.x;
    const int mb = blockIdx.x >> 3;
    const int nb = blockIdx.x & 7;
    const int m0 = mb * 64;
    const bool isT = (nb < 4);
    const int n0l = isT ? nb * 64 : (nb - 4) * 64;
    const unsigned short* pB1 = wtp + (isT ? 0 : 2 * 65536);
    const unsigned short* pB2 = pB1 + 65536;

    const int w    = tid >> 6;
    const int lane = tid & 63;
    const int quad = lane >> 4;
    const int l15  = lane & 15;

    f32x4 acc[4];
#pragma unroll
    for (int i = 0; i < 4; i++) acc[i] = (f32x4){0.f, 0.f, 0.f, 0.f};

    const int ssel = tid >> 7;
    const int spl  = (tid >> 6) & 1;
    const int srow = (tid & 63) >> 2;
    const int sseg = tid & 3;
    const unsigned short* gsrc =
        (ssel == 0) ? (spl ? h2 : h1) : (spl ? pB2 : pB1);
    const int growbase = (ssel == 0) ? m0 : n0l;
    char* ldsdst = lds + (ssel * 2 + spl) * 5120;

    for (int ks = 0; ks < 256; ks += 32) {
        __syncthreads();
#pragma unroll
        for (int i = 0; i < 4; i++) {
            const int row = srow + i * 16;
            uint4 v = *(const uint4*)&gsrc[(growbase + row) * 256 + ks + sseg * 8];
            *(uint4*)(ldsdst + row * 80 + sseg * 16) = v;
        }
        __syncthreads();

        const char* Ab = lds;
        const char* Bb = lds + 10240;
        const short8 b1 = *(const short8*)(Bb + (w * 16 + l15) * 80 + quad * 16);
        const short8 b2 = *(const short8*)(Bb + 5120 + (w * 16 + l15) * 80 + quad * 16);
#pragma unroll
        for (int mt = 0; mt < 4; mt++) {
            const short8 a1 = *(const short8*)(Ab + (mt * 16 + l15) * 80 + quad * 16);
            const short8 a2 = *(const short8*)(Ab + 5120 + (mt * 16 + l15) * 80 + quad * 16);
            acc[mt] = __builtin_amdgcn_mfma_f32_16x16x32_bf16(a1, b1, acc[mt], 0, 0, 0);
            acc[mt] = __builtin_amdgcn_mfma_f32_16x16x32_bf16(a1, b2, acc[mt], 0, 0, 0);
            acc[mt] = __builtin_amdgcn_mfma_f32_16x16x32_bf16(a2, b1, acc[mt], 0, 0, 0);
        }
    }

    __syncthreads();
    float* ct = (float*)lds;
#pragma unroll
    for (int mt = 0; mt < 4; mt++)
#pragma unroll
        for (int r = 0; r < 4; r++)
            ct[(mt * 16 + quad * 4 + r) * 68 + w * 16 + l15] = acc[mt][r];
    __syncthreads();

    const int b  = m0 >> 9;
    const int s0 = m0 & 511;
    if (isT) {
        const int n0g = nb * 64;
#pragma unroll
        for (int i = 0; i < 4; i++) {
            const int item = tid + i * 256;
            const int mr = item >> 4, nq = item & 15;
            const float4 c  = *(const float4*)&ct[mr * 68 + nq * 4];
            const float4 bv = *(const float4*)&bh[n0g + nq * 4];
            float4 o;
            o.x = __builtin_amdgcn_exp2f((c.x + bv.x) * CC);
            o.y = __builtin_amdgcn_exp2f((c.y + bv.y) * CC);
            o.z = __builtin_amdgcn_exp2f((c.z + bv.z) * CC);
            o.w = __builtin_amdgcn_exp2f((c.w + bv.w) * CC);
            *(float4*)&Egt[(m0 + mr) * Hn + n0g + nq * 4] = o;
        }
    } else {
        const int kq0 = (nb - 4) * 16;
#pragma unroll
        for (int i = 0; i < 4; i++) {
            const int item = tid + i * 256;
            const int mr = item & 63, nq = item >> 6;
            const float4 c = *(const float4*)&ct[mr * 68 + nq * 4];
            float4 o;
            o.x = __builtin_amdgcn_exp2f(c.x * CC);
            o.y = __builtin_amdgcn_exp2f(c.y * CC);
            o.z = __builtin_amdgcn_exp2f(c.z * CC);
            o.w = __builtin_amdgcn_exp2f(c.w * CC);
            *(float4*)&Egp4[b * 131072 + (kq0 + nq) * 2048 + (s0 + mr) * 4] = o;
        }
    }
}

// ---------------------------------------------------------------------------
// attn: fused score + softmax + out, 4 t-rows per block -> 512 blocks
// (2 blocks/CU; R7's 8-row had 1 blk/CU, occ 19%). Inner loop in packed-f32
// pairs (v_pk_fma_f32 path): acc kept as f32x2, 2 pk_fma + 2 pk_mul +
// 5 scalar mul + 1 rcp per 4 elements.
// ---------------------------------------------------------------------------
__global__ __launch_bounds__(512) void attn_kernel(
    const float* __restrict__ hsrc, const float* __restrict__ Egt,
    const float* __restrict__ Egp4, const float* __restrict__ wa2,
    const float* __restrict__ cst,
    float* __restrict__ out, float* __restrict__ out_attn)
{
    // layout: [0,8K) egt4(4K)+free / phase2 attn_l 8K ; [8K,9K) wal ;
    //         [9.25K..) red ; [10K,26K) part (16K)
    __shared__ char smem[26624];
    float*  egt4   = (float*)smem;
    float*  attn_l = (float*)smem;
    float*  wal    = (float*)(smem + 8192);
    float*  red    = (float*)(smem + 9472);
    float4* part   = (float4*)(smem + 10240);

    const int tid = threadIdx.x;
    const int b   = blockIdx.x & 3;
    const int t0  = (blockIdx.x >> 2) << 2;

    for (int i = tid; i < 4 * Hn; i += 512)
        egt4[i] = Egt[(b * Sn + t0) * Hn + i];
    if (tid < 256) wal[tid] = wa2[tid];
    __syncthreads();

    const float4* __restrict__ ep = (const float4*)(Egp4 + b * (Hn * Sn));

    f32x2 accA[4], accB[4];
#pragma unroll
    for (int r = 0; r < 4; r++) { accA[r] = (f32x2){0.f, 0.f}; accB[r] = (f32x2){0.f, 0.f}; }

    float4 cur = ep[tid];
    float4 nxt = ep[Sn + tid];
    for (int k4 = 0; k4 < 64; k4++) {
        const float4 nn = ep[((k4 + 2) & 63) * Sn + tid];
        const float4 w4 = *(const float4*)&wal[k4 * 4];
        const f32x2 wa01 = (f32x2){w4.x, w4.y};
        const f32x2 wa23 = (f32x2){w4.z, w4.w};
        const f32x2 ep01 = (f32x2){cur.x, cur.y};
        const f32x2 ep23 = (f32x2){cur.z, cur.w};
#pragma unroll
        for (int r = 0; r < 4; r++) {
            const float4 eg = *(const float4*)&egt4[r * Hn + k4 * 4]; // bcast b128
            const f32x2 d01 = ep01 * (f32x2){eg.x, eg.y} + (f32x2){1.f, 1.f};
            const f32x2 d23 = ep23 * (f32x2){eg.z, eg.w} + (f32x2){1.f, 1.f};
            const float p01 = d01.x * d01.y;
            const float p23 = d23.x * d23.y;
            const float rr  = __builtin_amdgcn_rcpf(p01 * p23);
            const float q23 = p23 * rr;     // = 1/p01
            const float q01 = p01 * rr;     // = 1/p23
            const f32x2 m01 = wa01 * (f32x2){d01.y, d01.x};
            const f32x2 m23 = wa23 * (f32x2){d23.y, d23.x};
            accA[r] = accA[r] + m01 * (f32x2){q23, q23};
            accB[r] = accB[r] + m23 * (f32x2){q01, q01};
        }
        cur = nxt; nxt = nn;
    }

    // sigmoid of score, then exp for softmax (sig in (0,1): no max-sub)
    const float k0 = cst[0];
    float ex[4];
#pragma unroll
    for (int r = 0; r < 4; r++) {
        const float a = (accA[r].x + accA[r].y) + (accB[r].x + accB[r].y);
        const float e1  = __builtin_amdgcn_exp2f(fmaf(-L2E, a, k0));
        const float sig = __builtin_amdgcn_rcpf(1.0f + e1);
        ex[r] = __builtin_amdgcn_exp2f(L2E * sig);
    }

    const int lane = tid & 63, wid = tid >> 6;
#pragma unroll
    for (int r = 0; r < 4; r++) {
        float v = ex[r];
#pragma unroll
        for (int off = 32; off >= 1; off >>= 1) v += __shfl_xor(v, off, 64);
        if (lane == 0) red[r * 8 + wid] = v;
    }
    __syncthreads();   // all waves past k4 loop (egt4 dead); red visible

#pragma unroll
    for (int r = 0; r < 4; r++) {
        float tot = 0.f;
#pragma unroll
        for (int i = 0; i < 8; i++) tot += red[r * 8 + i];
        const float a = ex[r] * __builtin_amdgcn_rcpf(tot);
        attn_l[r * Sn + tid] = a;                       // aliases egt4 (dead)
        out_attn[(b * Sn + t0 + r) * Sn + tid] = a;
    }
    __syncthreads();

    // ---- phase 2: out rows = attn @ h ----
    const int c4 = tid & 63;
    const int q  = __builtin_amdgcn_readfirstlane(tid >> 6);   // 0..7

    const float* __restrict__ hb = hsrc + (b * Sn + q * 64) * Hn + c4 * 4;

    float4 a[4];
#pragma unroll
    for (int r = 0; r < 4; r++) a[r] = (float4){0.f, 0.f, 0.f, 0.f};

#pragma unroll 2
    for (int j4 = 0; j4 < 16; j4++) {
        float4 wv[4];
#pragma unroll
        for (int r = 0; r < 4; r++)
            wv[r] = *(const float4*)&attn_l[r * Sn + q * 64 + j4 * 4];  // bcast
#pragma unroll
        for (int i = 0; i < 4; i++) {
            const float4 hv = *(const float4*)&hb[(j4 * 4 + i) * Hn];
#pragma unroll
            for (int r = 0; r < 4; r++) {
                const float wr = ((const float*)&wv[r])[i];
                a[r].x = fmaf(wr, hv.x, a[r].x);
                a[r].y = fmaf(wr, hv.y, a[r].y);
                a[r].z = fmaf(wr, hv.z, a[r].z);
                a[r].w = fmaf(wr, hv.w, a[r].w);
            }
        }
    }
    __syncthreads();   // attn_l reads done

    if (q < 4) {
#pragma unroll
        for (int r = 0; r < 4; r++) part[(q * 4 + r) * 64 + c4] = a[r];
    }
    __syncthreads();
    if (q >= 4) {
#pragma unroll
        for (int r = 0; r < 4; r++) {
            float4 p = part[((q - 4) * 4 + r) * 64 + c4];
            p.x += a[r].x; p.y += a[r].y; p.z += a[r].z; p.w += a[r].w;
            part[((q - 4) * 4 + r) * 64 + c4] = p;
        }
    }
    __syncthreads();

    const int col = tid & 255;
    const int rh  = tid >> 8;
    const float* pf = (const float*)part;
#pragma unroll
    for (int rr = 0; rr < 2; rr++) {
        const int r = rh * 2 + rr;
        float s = 0.f;
#pragma unroll
        for (int qq = 0; qq < 4; qq++)
            s += pf[((qq * 4 + r) * 64 + (col >> 2)) * 4 + (col & 3)];
        out[(b * Sn + t0 + r) * Hn + col] = s;
    }
}

extern "C" void kernel_launch(void* const* d_in, const int* in_sizes, int n_in,
                              void* d_out, int out_size, void* d_ws, size_t ws_size,
                              hipStream_t stream) {
    const float* h   = (const float*)d_in[0];
    const float* Wt  = (const float*)d_in[1];
    const float* Wtp = (const float*)d_in[2];
    const float* bh  = (const float*)d_in[3];
    const float* Wa  = (const float*)d_in[4];
    const float* ba  = (const float*)d_in[5];

    float* out      = (float*)d_out;                 // (B,S,H) = 524288
    float* out_attn = out + Bn * Sn * Hn;            // (B,S,S) = 1048576

    float* ws   = (float*)d_ws;
    float* Egt  = ws;                                 // 524288 f
    float* Egp4 = ws + 524288;                        // 524288 f
    float* wa2  = ws + 1048576;                       // 256 f
    float* cst  = ws + 1048832;                       // 1 f
    unsigned short* h1  = (unsigned short*)(ws + 1048840);   // 524288 us
    unsigned short* h2  = h1 + 2048 * 256;                   // 524288 us
    unsigned short* wtp = h2 + 2048 * 256;                   // 4 x 65536 us

    prep_kernel<<<dim3(288), dim3(256), 0, stream>>>(
        h, Wt, Wtp, Wa, ba, h1, h2, wtp, wa2, cst);
    gemm_kernel<<<dim3(256), dim3(256), 0, stream>>>(h1, h2, wtp, bh, Egt, Egp4);
    attn_kernel<<<dim3(Bn * (Sn / 4)), dim3(512), 0, stream>>>(
        h, Egt, Egp4, wa2, cst, out, out_attn);
}

// Round 9
// 118.897 us; speedup vs baseline: 1.0526x; 1.0446x over previous
//
#include <hip/hip_runtime.h>

// Problem constants: B=4, S=512, H=256
#define Bn 4
#define Sn 512
#define Hn 256

#define CC   2.8853900817779268f   // 2*log2(e)
#define L2E  1.4426950408889634f

typedef __attribute__((ext_vector_type(4))) float f32x4;
typedef __attribute__((ext_vector_type(8))) short short8;

__device__ __forceinline__ unsigned short bf16rn(float f) {
    unsigned int u = __float_as_uint(f);
    u += 0x7fffu + ((u >> 16) & 1u);
    return (unsigned short)(u >> 16);
}
__device__ __forceinline__ float bf16tof(unsigned short b) {
    return __uint_as_float(((unsigned int)b) << 16);
}

// ---------------------------------------------------------------------------
// prep: merged splitA (h -> h1,h2 bf16 planes; 256 blocks) and splitB
// (Wt/Wp -> transposed bf16 split planes; 32 blocks). 288 blocks x 256 thr.
// ---------------------------------------------------------------------------
__global__ __launch_bounds__(256) void prep_kernel(
    const float* __restrict__ h,  const float* __restrict__ Wt,
    const float* __restrict__ Wp, const float* __restrict__ Wa,
    const float* __restrict__ ba,
    unsigned short* __restrict__ h1, unsigned short* __restrict__ h2,
    unsigned short* __restrict__ wtp,
    float* __restrict__ wa2, float* __restrict__ cst)
{
    __shared__ float tile[64 * 68];
    __shared__ float red4[4];
    const int tid = threadIdx.x;
    const int bid = blockIdx.x;

    if (bid < 256) {
        const int base = (bid * 256 + tid) * 8;
        float4 v0 = *(const float4*)&h[base];
        float4 v1 = *(const float4*)&h[base + 4];
        float f[8] = {v0.x, v0.y, v0.z, v0.w, v1.x, v1.y, v1.z, v1.w};
        unsigned short b1[8], b2[8];
#pragma unroll
        for (int i = 0; i < 8; i++) {
            b1[i] = bf16rn(f[i]);
            b2[i] = bf16rn(f[i] - bf16tof(b1[i]));
        }
        uint4 u1, u2;
        u1.x = (unsigned)b1[0] | ((unsigned)b1[1] << 16);
        u1.y = (unsigned)b1[2] | ((unsigned)b1[3] << 16);
        u1.z = (unsigned)b1[4] | ((unsigned)b1[5] << 16);
        u1.w = (unsigned)b1[6] | ((unsigned)b1[7] << 16);
        u2.x = (unsigned)b2[0] | ((unsigned)b2[1] << 16);
        u2.y = (unsigned)b2[2] | ((unsigned)b2[3] << 16);
        u2.z = (unsigned)b2[4] | ((unsigned)b2[5] << 16);
        u2.w = (unsigned)b2[6] | ((unsigned)b2[7] << 16);
        *(uint4*)&h1[base] = u1;
        *(uint4*)&h2[base] = u2;

        if (bid == 0) {
            float w = Wa[tid];
#pragma unroll
            for (int off = 32; off >= 1; off >>= 1) w += __shfl_xor(w, off, 64);
            if ((tid & 63) == 0) red4[tid >> 6] = w;
            __syncthreads();
            wa2[tid] = -2.0f * Wa[tid];
            if (tid == 0)
                cst[0] = -L2E * ((red4[0] + red4[1] + red4[2] + red4[3]) + ba[0]);
        }
    } else {
        const int sb  = bid - 256;
        const int mat = sb >> 4;
        const int t4  = sb & 15;
        const int k0  = (t4 >> 2) * 64, n0 = (t4 & 3) * 64;
        const float* __restrict__ W = mat ? Wp : Wt;

#pragma unroll
        for (int i = 0; i < 4; i++) {
            const int idx = tid + 256 * i;
            const int kr = idx >> 4, nq = idx & 15;
            *(float4*)&tile[kr * 68 + nq * 4] =
                *(const float4*)&W[(k0 + kr) * Hn + n0 + nq * 4];
        }
        __syncthreads();

        unsigned short* p1 = wtp + mat * 2 * 65536;
        unsigned short* p2 = p1 + 65536;
#pragma unroll
        for (int i = 0; i < 8; i++) {
            const int idx = tid + 256 * i;
            const int n = idx >> 5, kp = idx & 31;
            const float f0 = tile[(2 * kp) * 68 + n];
            const float f1 = tile[(2 * kp + 1) * 68 + n];
            const unsigned short a0 = bf16rn(f0), a1 = bf16rn(f1);
            const unsigned short c0 = bf16rn(f0 - bf16tof(a0));
            const unsigned short c1 = bf16rn(f1 - bf16tof(a1));
            const int dw = ((n0 + n) * 256 + k0) / 2 + kp;
            ((unsigned int*)p1)[dw] = (unsigned)a0 | ((unsigned)a1 << 16);
            ((unsigned int*)p2)[dw] = (unsigned)c0 | ((unsigned)c1 << 16);
        }
    }
}

// ---------------------------------------------------------------------------
// gemm: C[2048][512] = h @ [Wt|Wp] via 16x16x32 bf16 MFMA, split-precision
// (a1w1 + a1w2 + a2w1). Fused exp2 epilogue -> Egt / Egp4. 256 blk x 256 thr.
// ---------------------------------------------------------------------------
__global__ __launch_bounds__(256) void gemm_kernel(
    const unsigned short* __restrict__ h1, const unsigned short* __restrict__ h2,
    const unsigned short* __restrict__ wtp, const float* __restrict__ bh,
    float* __restrict__ Egt, float* __restrict__ Egp4)
{
    __shared__ char lds[20480];

    const int tid = threadIdx.x;
    const int mb = blockIdx.x >> 3;
    const int nb = blockIdx.x & 7;
    const int m0 = mb * 64;
    const bool isT = (nb < 4);
    const int n0l = isT ? nb * 64 : (nb - 4) * 64;
    const unsigned short* pB1 = wtp + (isT ? 0 : 2 * 65536);
    const unsigned short* pB2 = pB1 + 65536;

    const int w    = tid >> 6;
    const int lane = tid & 63;
    const int quad = lane >> 4;
    const int l15  = lane & 15;

    f32x4 acc[4];
#pragma unroll
    for (int i = 0; i < 4; i++) acc[i] = (f32x4){0.f, 0.f, 0.f, 0.f};

    const int ssel = tid >> 7;
    const int spl  = (tid >> 6) & 1;
    const int srow = (tid & 63) >> 2;
    const int sseg = tid & 3;
    const unsigned short* gsrc =
        (ssel == 0) ? (spl ? h2 : h1) : (spl ? pB2 : pB1);
    const int growbase = (ssel == 0) ? m0 : n0l;
    char* ldsdst = lds + (ssel * 2 + spl) * 5120;

    for (int ks = 0; ks < 256; ks += 32) {
        __syncthreads();
#pragma unroll
        for (int i = 0; i < 4; i++) {
            const int row = srow + i * 16;
            uint4 v = *(const uint4*)&gsrc[(growbase + row) * 256 + ks + sseg * 8];
            *(uint4*)(ldsdst + row * 80 + sseg * 16) = v;
        }
        __syncthreads();

        const char* Ab = lds;
        const char* Bb = lds + 10240;
        const short8 b1 = *(const short8*)(Bb + (w * 16 + l15) * 80 + quad * 16);
        const short8 b2 = *(const short8*)(Bb + 5120 + (w * 16 + l15) * 80 + quad * 16);
#pragma unroll
        for (int mt = 0; mt < 4; mt++) {
            const short8 a1 = *(const short8*)(Ab + (mt * 16 + l15) * 80 + quad * 16);
            const short8 a2 = *(const short8*)(Ab + 5120 + (mt * 16 + l15) * 80 + quad * 16);
            acc[mt] = __builtin_amdgcn_mfma_f32_16x16x32_bf16(a1, b1, acc[mt], 0, 0, 0);
            acc[mt] = __builtin_amdgcn_mfma_f32_16x16x32_bf16(a1, b2, acc[mt], 0, 0, 0);
            acc[mt] = __builtin_amdgcn_mfma_f32_16x16x32_bf16(a2, b1, acc[mt], 0, 0, 0);
        }
    }

    __syncthreads();
    float* ct = (float*)lds;
#pragma unroll
    for (int mt = 0; mt < 4; mt++)
#pragma unroll
        for (int r = 0; r < 4; r++)
            ct[(mt * 16 + quad * 4 + r) * 68 + w * 16 + l15] = acc[mt][r];
    __syncthreads();

    const int b  = m0 >> 9;
    const int s0 = m0 & 511;
    if (isT) {
        const int n0g = nb * 64;
#pragma unroll
        for (int i = 0; i < 4; i++) {
            const int item = tid + i * 256;
            const int mr = item >> 4, nq = item & 15;
            const float4 c  = *(const float4*)&ct[mr * 68 + nq * 4];
            const float4 bv = *(const float4*)&bh[n0g + nq * 4];
            float4 o;
            o.x = __builtin_amdgcn_exp2f((c.x + bv.x) * CC);
            o.y = __builtin_amdgcn_exp2f((c.y + bv.y) * CC);
            o.z = __builtin_amdgcn_exp2f((c.z + bv.z) * CC);
            o.w = __builtin_amdgcn_exp2f((c.w + bv.w) * CC);
            *(float4*)&Egt[(m0 + mr) * Hn + n0g + nq * 4] = o;
        }
    } else {
        const int kq0 = (nb - 4) * 16;
#pragma unroll
        for (int i = 0; i < 4; i++) {
            const int item = tid + i * 256;
            const int mr = item & 63, nq = item >> 6;
            const float4 c = *(const float4*)&ct[mr * 68 + nq * 4];
            float4 o;
            o.x = __builtin_amdgcn_exp2f(c.x * CC);
            o.y = __builtin_amdgcn_exp2f(c.y * CC);
            o.z = __builtin_amdgcn_exp2f(c.z * CC);
            o.w = __builtin_amdgcn_exp2f(c.w * CC);
            *(float4*)&Egp4[b * 131072 + (kq0 + nq) * 2048 + (s0 + mr) * 4] = o;
        }
    }
}

// ---------------------------------------------------------------------------
// attn: fused score + softmax + out. 1024 threads = (tp:512) x (kh:2 k-halves),
// 4 t-rows, grid 512 -> 2 blocks/CU x 16 waves = 32 waves/CU (100% occupancy;
// R8 had 16 waves/CU at occ 31%). kh=1 writes partial accs to LDS; kh=0
// combines + sigmoid + softmax. Phase 2: 16 q-groups x 32 tp, 8->1 reduction.
// ---------------------------------------------------------------------------
__global__ __launch_bounds__(1024) void attn_kernel(
    const float* __restrict__ hsrc, const float* __restrict__ Egt,
    const float* __restrict__ Egp4, const float* __restrict__ wa2,
    const float* __restrict__ cst,
    float* __restrict__ out, float* __restrict__ out_attn)
{
    // [0,8K) attn_l[4][512] ; [8K,12K) egt4 ; [12K,13K) wal ;
    // [13K,21K) accl[4][512] (kh=1 partials) ; [21K,21.25K) red ;
    // part[8][4][64]f4 32KB aliases [8K,40K) (phase 2 only; all dead by then)
    __shared__ char smem[40960];
    float*  attn_l = (float*)smem;
    float*  egt4   = (float*)(smem + 8192);
    float*  wal    = (float*)(smem + 12288);
    float*  accl   = (float*)(smem + 13312);
    float*  red    = (float*)(smem + 21504);
    float4* part   = (float4*)(smem + 8192);

    const int tid = threadIdx.x;       // 0..1023
    const int tp  = tid & 511;
    const int kh  = tid >> 9;          // 0 or 1: k-half
    const int b   = blockIdx.x & 3;
    const int t0  = (blockIdx.x >> 2) << 2;

    egt4[tid & 1023] = Egt[(b * Sn + t0) * Hn + (tid & 1023)];  // 4 rows x 256
    if (tid < 256) wal[tid] = wa2[tid];
    __syncthreads();

    const float4* __restrict__ ep = (const float4*)(Egp4 + b * (Hn * Sn));
    const int kb = kh * 32;            // k4 base for this half

    float acc[4] = {0.f, 0.f, 0.f, 0.f};

#pragma unroll 2
    for (int kk = 0; kk < 32; kk++) {
        const int k4 = kb + kk;
        const float4 cur = ep[k4 * Sn + tp];           // coalesced, L2
        const float4 w4  = *(const float4*)&wal[k4 * 4];
#pragma unroll
        for (int r = 0; r < 4; r++) {
            const float4 eg = *(const float4*)&egt4[r * Hn + k4 * 4]; // bcast b128
            const float d1 = fmaf(cur.x, eg.x, 1.0f);
            const float d2 = fmaf(cur.y, eg.y, 1.0f);
            const float d3 = fmaf(cur.z, eg.z, 1.0f);
            const float d4 = fmaf(cur.w, eg.w, 1.0f);
            const float p12 = d1 * d2, p34 = d3 * d4;
            const float n12 = fmaf(w4.x, d2, w4.y * d1);
            const float n34 = fmaf(w4.z, d4, w4.w * d3);
            const float num = fmaf(n12, p34, n34 * p12);
            acc[r] = fmaf(num, __builtin_amdgcn_rcpf(p12 * p34), acc[r]);
        }
    }

    if (kh == 1) {
#pragma unroll
        for (int r = 0; r < 4; r++) accl[r * 512 + tp] = acc[r];
    }
    __syncthreads();

    float ex[4];
    const float k0 = cst[0];
    if (kh == 0) {
#pragma unroll
        for (int r = 0; r < 4; r++) {
            const float a   = acc[r] + accl[r * 512 + tp];
            const float e1  = __builtin_amdgcn_exp2f(fmaf(-L2E, a, k0));
            const float sig = __builtin_amdgcn_rcpf(1.0f + e1);
            ex[r] = __builtin_amdgcn_exp2f(L2E * sig);   // sig in (0,1)
        }
        const int lane = tid & 63, wid = tid >> 6;       // wid 0..7
#pragma unroll
        for (int r = 0; r < 4; r++) {
            float v = ex[r];
#pragma unroll
            for (int off = 32; off >= 1; off >>= 1) v += __shfl_xor(v, off, 64);
            if (lane == 0) red[r * 8 + wid] = v;
        }
    }
    __syncthreads();

    if (kh == 0) {
#pragma unroll
        for (int r = 0; r < 4; r++) {
            float tot = 0.f;
#pragma unroll
            for (int i = 0; i < 8; i++) tot += red[r * 8 + i];
            const float a = ex[r] * __builtin_amdgcn_rcpf(tot);
            attn_l[r * Sn + tp] = a;
            out_attn[(b * Sn + t0 + r) * Sn + tp] = a;
        }
    }
    __syncthreads();

    // ---- phase 2: out rows = attn @ h. 16 q-groups of 32 t' each ----
    const int c4 = tid & 63;
    const int q  = tid >> 6;                 // 0..15, wave-uniform

    const float* __restrict__ hb = hsrc + (b * Sn + q * 32) * Hn + c4 * 4;

    float4 a4[4];
#pragma unroll
    for (int r = 0; r < 4; r++) a4[r] = (float4){0.f, 0.f, 0.f, 0.f};

#pragma unroll 2
    for (int j4 = 0; j4 < 8; j4++) {
        float4 wv[4];
#pragma unroll
        for (int r = 0; r < 4; r++)
            wv[r] = *(const float4*)&attn_l[r * Sn + q * 32 + j4 * 4];  // bcast
#pragma unroll
        for (int i = 0; i < 4; i++) {
            const float4 hv = *(const float4*)&hb[(j4 * 4 + i) * Hn];
#pragma unroll
            for (int r = 0; r < 4; r++) {
                const float wr = ((const float*)&wv[r])[i];
                a4[r].x = fmaf(wr, hv.x, a4[r].x);
                a4[r].y = fmaf(wr, hv.y, a4[r].y);
                a4[r].z = fmaf(wr, hv.z, a4[r].z);
                a4[r].w = fmaf(wr, hv.w, a4[r].w);
            }
        }
    }
    __syncthreads();   // egt4/wal/accl/red reads all done; part may now alias

    if (q < 8) {
#pragma unroll
        for (int r = 0; r < 4; r++) part[(q * 4 + r) * 64 + c4] = a4[r];
    }
    __syncthreads();
    if (q >= 8) {
#pragma unroll
        for (int r = 0; r < 4; r++) {
            float4 p = part[((q - 8) * 4 + r) * 64 + c4];
            p.x += a4[r].x; p.y += a4[r].y; p.z += a4[r].z; p.w += a4[r].w;
            part[((q - 8) * 4 + r) * 64 + c4] = p;
        }
    }
    __syncthreads();

    // final: 1024 threads = 256 cols x 4 rows; sum the 8 q-partials
    {
        const int col = tid & 255;
        const int r   = tid >> 8;
        const float* pf = (const float*)part;
        float s = 0.f;
#pragma unroll
        for (int qq = 0; qq < 8; qq++)
            s += pf[((qq * 4 + r) * 64 + (col >> 2)) * 4 + (col & 3)];
        out[(b * Sn + t0 + r) * Hn + col] = s;
    }
}

extern "C" void kernel_launch(void* const* d_in, const int* in_sizes, int n_in,
                              void* d_out, int out_size, void* d_ws, size_t ws_size,
                              hipStream_t stream) {
    const float* h   = (const float*)d_in[0];
    const float* Wt  = (const float*)d_in[1];
    const float* Wtp = (const float*)d_in[2];
    const float* bh  = (const float*)d_in[3];
    const float* Wa  = (const float*)d_in[4];
    const float* ba  = (const float*)d_in[5];

    float* out      = (float*)d_out;                 // (B,S,H) = 524288
    float* out_attn = out + Bn * Sn * Hn;            // (B,S,S) = 1048576

    float* ws   = (float*)d_ws;
    float* Egt  = ws;                                 // 524288 f
    float* Egp4 = ws + 524288;                        // 524288 f
    float* wa2  = ws + 1048576;                       // 256 f
    float* cst  = ws + 1048832;                       // 1 f
    unsigned short* h1  = (unsigned short*)(ws + 1048840);   // 524288 us
    unsigned short* h2  = h1 + 2048 * 256;                   // 524288 us
    unsigned short* wtp = h2 + 2048 * 256;                   // 4 x 65536 us

    prep_kernel<<<dim3(288), dim3(256), 0, stream>>>(
        h, Wt, Wtp, Wa, ba, h1, h2, wtp, wa2, cst);
    gemm_kernel<<<dim3(256), dim3(256), 0, stream>>>(h1, h2, wtp, bh, Egt, Egp4);
    attn_kernel<<<dim3(Bn * (Sn / 4)), dim3(1024), 0, stream>>>(
        h, Egt, Egp4, wa2, cst, out, out_attn);
}

// Round 10
// 116.037 us; speedup vs baseline: 1.0785x; 1.0246x over previous
//
#include <hip/hip_runtime.h>

// Problem constants: B=4, S=512, H=256
#define Bn 4
#define Sn 512
#define Hn 256

#define CC   2.8853900817779268f   // 2*log2(e)
#define L2E  1.4426950408889634f

typedef __attribute__((ext_vector_type(4))) float f32x4;
typedef __attribute__((ext_vector_type(8))) short short8;

__device__ __forceinline__ unsigned short bf16rn(float f) {
    unsigned int u = __float_as_uint(f);
    u += 0x7fffu + ((u >> 16) & 1u);
    return (unsigned short)(u >> 16);
}
__device__ __forceinline__ float bf16tof(unsigned short b) {
    return __uint_as_float(((unsigned int)b) << 16);
}

// ---------------------------------------------------------------------------
// prep: merged splitA (h -> h1,h2 bf16 planes; 256 blocks) and splitB
// (Wt/Wp -> transposed bf16 split planes; 32 blocks). 288 blocks x 256 thr.
// ---------------------------------------------------------------------------
__global__ __launch_bounds__(256) void prep_kernel(
    const float* __restrict__ h,  const float* __restrict__ Wt,
    const float* __restrict__ Wp, const float* __restrict__ Wa,
    const float* __restrict__ ba,
    unsigned short* __restrict__ h1, unsigned short* __restrict__ h2,
    unsigned short* __restrict__ wtp,
    float* __restrict__ wa2, float* __restrict__ cst)
{
    __shared__ float tile[64 * 68];
    __shared__ float red4[4];
    const int tid = threadIdx.x;
    const int bid = blockIdx.x;

    if (bid < 256) {
        const int base = (bid * 256 + tid) * 8;
        float4 v0 = *(const float4*)&h[base];
        float4 v1 = *(const float4*)&h[base + 4];
        float f[8] = {v0.x, v0.y, v0.z, v0.w, v1.x, v1.y, v1.z, v1.w};
        unsigned short b1[8], b2[8];
#pragma unroll
        for (int i = 0; i < 8; i++) {
            b1[i] = bf16rn(f[i]);
            b2[i] = bf16rn(f[i] - bf16tof(b1[i]));
        }
        uint4 u1, u2;
        u1.x = (unsigned)b1[0] | ((unsigned)b1[1] << 16);
        u1.y = (unsigned)b1[2] | ((unsigned)b1[3] << 16);
        u1.z = (unsigned)b1[4] | ((unsigned)b1[5] << 16);
        u1.w = (unsigned)b1[6] | ((unsigned)b1[7] << 16);
        u2.x = (unsigned)b2[0] | ((unsigned)b2[1] << 16);
        u2.y = (unsigned)b2[2] | ((unsigned)b2[3] << 16);
        u2.z = (unsigned)b2[4] | ((unsigned)b2[5] << 16);
        u2.w = (unsigned)b2[6] | ((unsigned)b2[7] << 16);
        *(uint4*)&h1[base] = u1;
        *(uint4*)&h2[base] = u2;

        if (bid == 0) {
            float w = Wa[tid];
#pragma unroll
            for (int off = 32; off >= 1; off >>= 1) w += __shfl_xor(w, off, 64);
            if ((tid & 63) == 0) red4[tid >> 6] = w;
            __syncthreads();
            wa2[tid] = -2.0f * Wa[tid];
            if (tid == 0)
                cst[0] = -L2E * ((red4[0] + red4[1] + red4[2] + red4[3]) + ba[0]);
        }
    } else {
        const int sb  = bid - 256;
        const int mat = sb >> 4;
        const int t4  = sb & 15;
        const int k0  = (t4 >> 2) * 64, n0 = (t4 & 3) * 64;
        const float* __restrict__ W = mat ? Wp : Wt;

#pragma unroll
        for (int i = 0; i < 4; i++) {
            const int idx = tid + 256 * i;
            const int kr = idx >> 4, nq = idx & 15;
            *(float4*)&tile[kr * 68 + nq * 4] =
                *(const float4*)&W[(k0 + kr) * Hn + n0 + nq * 4];
        }
        __syncthreads();

        unsigned short* p1 = wtp + mat * 2 * 65536;
        unsigned short* p2 = p1 + 65536;
#pragma unroll
        for (int i = 0; i < 8; i++) {
            const int idx = tid + 256 * i;
            const int n = idx >> 5, kp = idx & 31;
            const float f0 = tile[(2 * kp) * 68 + n];
            const float f1 = tile[(2 * kp + 1) * 68 + n];
            const unsigned short a0 = bf16rn(f0), a1 = bf16rn(f1);
            const unsigned short c0 = bf16rn(f0 - bf16tof(a0));
            const unsigned short c1 = bf16rn(f1 - bf16tof(a1));
            const int dw = ((n0 + n) * 256 + k0) / 2 + kp;
            ((unsigned int*)p1)[dw] = (unsigned)a0 | ((unsigned)a1 << 16);
            ((unsigned int*)p2)[dw] = (unsigned)c0 | ((unsigned)c1 << 16);
        }
    }
}

// ---------------------------------------------------------------------------
// gemm: C[2048][512] = h @ [Wt|Wp] via 16x16x32 bf16 MFMA, split-precision
// (a1w1 + a1w2 + a2w1). Fused exp2 epilogue -> Egt / Egp4. 256 blk x 256 thr.
// ---------------------------------------------------------------------------
__global__ __launch_bounds__(256) void gemm_kernel(
    const unsigned short* __restrict__ h1, const unsigned short* __restrict__ h2,
    const unsigned short* __restrict__ wtp, const float* __restrict__ bh,
    float* __restrict__ Egt, float* __restrict__ Egp4)
{
    __shared__ char lds[20480];

    const int tid = threadIdx.x;
    const int mb = blockIdx.x >> 3;
    const int nb = blockIdx.x & 7;
    const int m0 = mb * 64;
    const bool isT = (nb < 4);
    const int n0l = isT ? nb * 64 : (nb - 4) * 64;
    const unsigned short* pB1 = wtp + (isT ? 0 : 2 * 65536);
    const unsigned short* pB2 = pB1 + 65536;

    const int w    = tid >> 6;
    const int lane = tid & 63;
    const int quad = lane >> 4;
    const int l15  = lane & 15;

    f32x4 acc[4];
#pragma unroll
    for (int i = 0; i < 4; i++) acc[i] = (f32x4){0.f, 0.f, 0.f, 0.f};

    const int ssel = tid >> 7;
    const int spl  = (tid >> 6) & 1;
    const int srow = (tid & 63) >> 2;
    const int sseg = tid & 3;
    const unsigned short* gsrc =
        (ssel == 0) ? (spl ? h2 : h1) : (spl ? pB2 : pB1);
    const int growbase = (ssel == 0) ? m0 : n0l;
    char* ldsdst = lds + (ssel * 2 + spl) * 5120;

    for (int ks = 0; ks < 256; ks += 32) {
        __syncthreads();
#pragma unroll
        for (int i = 0; i < 4; i++) {
            const int row = srow + i * 16;
            uint4 v = *(const uint4*)&gsrc[(growbase + row) * 256 + ks + sseg * 8];
            *(uint4*)(ldsdst + row * 80 + sseg * 16) = v;
        }
        __syncthreads();

        const char* Ab = lds;
        const char* Bb = lds + 10240;
        const short8 b1 = *(const short8*)(Bb + (w * 16 + l15) * 80 + quad * 16);
        const short8 b2 = *(const short8*)(Bb + 5120 + (w * 16 + l15) * 80 + quad * 16);
#pragma unroll
        for (int mt = 0; mt < 4; mt++) {
            const short8 a1 = *(const short8*)(Ab + (mt * 16 + l15) * 80 + quad * 16);
            const short8 a2 = *(const short8*)(Ab + 5120 + (mt * 16 + l15) * 80 + quad * 16);
            acc[mt] = __builtin_amdgcn_mfma_f32_16x16x32_bf16(a1, b1, acc[mt], 0, 0, 0);
            acc[mt] = __builtin_amdgcn_mfma_f32_16x16x32_bf16(a1, b2, acc[mt], 0, 0, 0);
            acc[mt] = __builtin_amdgcn_mfma_f32_16x16x32_bf16(a2, b1, acc[mt], 0, 0, 0);
        }
    }

    __syncthreads();
    float* ct = (float*)lds;
#pragma unroll
    for (int mt = 0; mt < 4; mt++)
#pragma unroll
        for (int r = 0; r < 4; r++)
            ct[(mt * 16 + quad * 4 + r) * 68 + w * 16 + l15] = acc[mt][r];
    __syncthreads();

    const int b  = m0 >> 9;
    const int s0 = m0 & 511;
    if (isT) {
        const int n0g = nb * 64;
#pragma unroll
        for (int i = 0; i < 4; i++) {
            const int item = tid + i * 256;
            const int mr = item >> 4, nq = item & 15;
            const float4 c  = *(const float4*)&ct[mr * 68 + nq * 4];
            const float4 bv = *(const float4*)&bh[n0g + nq * 4];
            float4 o;
            o.x = __builtin_amdgcn_exp2f((c.x + bv.x) * CC);
            o.y = __builtin_amdgcn_exp2f((c.y + bv.y) * CC);
            o.z = __builtin_amdgcn_exp2f((c.z + bv.z) * CC);
            o.w = __builtin_amdgcn_exp2f((c.w + bv.w) * CC);
            *(float4*)&Egt[(m0 + mr) * Hn + n0g + nq * 4] = o;
        }
    } else {
        const int kq0 = (nb - 4) * 16;
#pragma unroll
        for (int i = 0; i < 4; i++) {
            const int item = tid + i * 256;
            const int mr = item & 63, nq = item >> 6;
            const float4 c = *(const float4*)&ct[mr * 68 + nq * 4];
            float4 o;
            o.x = __builtin_amdgcn_exp2f(c.x * CC);
            o.y = __builtin_amdgcn_exp2f(c.y * CC);
            o.z = __builtin_amdgcn_exp2f(c.z * CC);
            o.w = __builtin_amdgcn_exp2f(c.w * CC);
            *(float4*)&Egp4[b * 131072 + (kq0 + nq) * 2048 + (s0 + mr) * 4] = o;
        }
    }
}

// ---------------------------------------------------------------------------
// attn: fused score + softmax + out. 1024 thr = (tp:512) x (kh:2), 4 t-rows,
// grid 512 -> 32 waves/CU. R10 change: egt/wa2 read via WAVE-UNIFORM GLOBAL
// addresses -> s_load_dwordx4 on the scalar pipe, freeing the LDS pipe
// (R9 issued 5 broadcast ds_read_b128 per wave per k4 = ~25us of LDS-pipe
// occupancy per CU; LDS was the phase-1 bottleneck, not VALU).
// ---------------------------------------------------------------------------
__global__ __launch_bounds__(1024) void attn_kernel(
    const float* __restrict__ hsrc, const float* __restrict__ Egt,
    const float* __restrict__ Egp4, const float* __restrict__ wa2,
    const float* __restrict__ cst,
    float* __restrict__ out, float* __restrict__ out_attn)
{
    // [0,8K) attn_l[4][512] ; [8K,16K) accl[4][512] ; [16K,16.25K) red ;
    // part[8][4][64]f4 32KB aliases [8K,40K) (phase 2 only; accl/red dead)
    __shared__ char smem[40960];
    float*  attn_l = (float*)smem;
    float*  accl   = (float*)(smem + 8192);
    float*  red    = (float*)(smem + 16384);
    float4* part   = (float4*)(smem + 8192);

    const int tid = threadIdx.x;       // 0..1023
    const int tp  = tid & 511;
    const int kh  = tid >> 9;          // 0 or 1: k-half (wave-uniform)
    const int b   = blockIdx.x & 3;
    const int t0  = (blockIdx.x >> 2) << 2;

    // wave-uniform scalar base for this half's k4 range
    const int kbu = __builtin_amdgcn_readfirstlane(kh << 5);

    const float* __restrict__ egt = Egt + (b * Sn + t0) * Hn;   // block-uniform
    const float4* __restrict__ ep = (const float4*)(Egp4 + b * (Hn * Sn));

    float acc[4] = {0.f, 0.f, 0.f, 0.f};

#pragma unroll 2
    for (int kk = 0; kk < 32; kk++) {
        const int k4 = kbu + kk;                       // wave-uniform
        const float4 cur = ep[k4 * Sn + tp];           // coalesced vector load
        const float4 w4  = *(const float4*)&wa2[k4 * 4];          // s_load
#pragma unroll
        for (int r = 0; r < 4; r++) {
            const float4 eg = *(const float4*)&egt[r * Hn + k4 * 4]; // s_load
            const float d1 = fmaf(cur.x, eg.x, 1.0f);
            const float d2 = fmaf(cur.y, eg.y, 1.0f);
            const float d3 = fmaf(cur.z, eg.z, 1.0f);
            const float d4 = fmaf(cur.w, eg.w, 1.0f);
            const float p12 = d1 * d2, p34 = d3 * d4;
            const float n12 = fmaf(w4.x, d2, w4.y * d1);
            const float n34 = fmaf(w4.z, d4, w4.w * d3);
            const float num = fmaf(n12, p34, n34 * p12);
            acc[r] = fmaf(num, __builtin_amdgcn_rcpf(p12 * p34), acc[r]);
        }
    }

    if (kh == 1) {
#pragma unroll
        for (int r = 0; r < 4; r++) accl[r * 512 + tp] = acc[r];
    }
    __syncthreads();

    float ex[4];
    const float k0 = cst[0];
    if (kh == 0) {
#pragma unroll
        for (int r = 0; r < 4; r++) {
            const float a   = acc[r] + accl[r * 512 + tp];
            const float e1  = __builtin_amdgcn_exp2f(fmaf(-L2E, a, k0));
            const float sig = __builtin_amdgcn_rcpf(1.0f + e1);
            ex[r] = __builtin_amdgcn_exp2f(L2E * sig);   // sig in (0,1)
        }
        const int lane = tid & 63, wid = tid >> 6;       // wid 0..7
#pragma unroll
        for (int r = 0; r < 4; r++) {
            float v = ex[r];
#pragma unroll
            for (int off = 32; off >= 1; off >>= 1) v += __shfl_xor(v, off, 64);
            if (lane == 0) red[r * 8 + wid] = v;
        }
    }
    __syncthreads();

    if (kh == 0) {
#pragma unroll
        for (int r = 0; r < 4; r++) {
            float tot = 0.f;
#pragma unroll
            for (int i = 0; i < 8; i++) tot += red[r * 8 + i];
            const float a = ex[r] * __builtin_amdgcn_rcpf(tot);
            attn_l[r * Sn + tp] = a;
            out_attn[(b * Sn + t0 + r) * Sn + tp] = a;
        }
    }
    __syncthreads();

    // ---- phase 2: out rows = attn @ h. 16 q-groups of 32 t' each ----
    const int c4 = tid & 63;
    const int q  = tid >> 6;                 // 0..15, wave-uniform

    const float* __restrict__ hb = hsrc + (b * Sn + q * 32) * Hn + c4 * 4;

    float4 a4[4];
#pragma unroll
    for (int r = 0; r < 4; r++) a4[r] = (float4){0.f, 0.f, 0.f, 0.f};

#pragma unroll 2
    for (int j4 = 0; j4 < 8; j4++) {
        float4 wv[4];
#pragma unroll
        for (int r = 0; r < 4; r++)
            wv[r] = *(const float4*)&attn_l[r * Sn + q * 32 + j4 * 4];  // bcast
#pragma unroll
        for (int i = 0; i < 4; i++) {
            const float4 hv = *(const float4*)&hb[(j4 * 4 + i) * Hn];
#pragma unroll
            for (int r = 0; r < 4; r++) {
                const float wr = ((const float*)&wv[r])[i];
                a4[r].x = fmaf(wr, hv.x, a4[r].x);
                a4[r].y = fmaf(wr, hv.y, a4[r].y);
                a4[r].z = fmaf(wr, hv.z, a4[r].z);
                a4[r].w = fmaf(wr, hv.w, a4[r].w);
            }
        }
    }
    __syncthreads();   // accl/red reads all done; part may now alias

    if (q < 8) {
#pragma unroll
        for (int r = 0; r < 4; r++) part[(q * 4 + r) * 64 + c4] = a4[r];
    }
    __syncthreads();
    if (q >= 8) {
#pragma unroll
        for (int r = 0; r < 4; r++) {
            float4 p = part[((q - 8) * 4 + r) * 64 + c4];
            p.x += a4[r].x; p.y += a4[r].y; p.z += a4[r].z; p.w += a4[r].w;
            part[((q - 8) * 4 + r) * 64 + c4] = p;
        }
    }
    __syncthreads();

    // final: 1024 threads = 256 cols x 4 rows; sum the 8 q-partials
    {
        const int col = tid & 255;
        const int r   = tid >> 8;
        const float* pf = (const float*)part;
        float s = 0.f;
#pragma unroll
        for (int qq = 0; qq < 8; qq++)
            s += pf[((qq * 4 + r) * 64 + (col >> 2)) * 4 + (col & 3)];
        out[(b * Sn + t0 + r) * Hn + col] = s;
    }
}

extern "C" void kernel_launch(void* const* d_in, const int* in_sizes, int n_in,
                              void* d_out, int out_size, void* d_ws, size_t ws_size,
                              hipStream_t stream) {
    const float* h   = (const float*)d_in[0];
    const float* Wt  = (const float*)d_in[1];
    const float* Wtp = (const float*)d_in[2];
    const float* bh  = (const float*)d_in[3];
    const float* Wa  = (const float*)d_in[4];
    const float* ba  = (const float*)d_in[5];

    float* out      = (float*)d_out;                 // (B,S,H) = 524288
    float* out_attn = out + Bn * Sn * Hn;            // (B,S,S) = 1048576

    float* ws   = (float*)d_ws;
    float* Egt  = ws;                                 // 524288 f
    float* Egp4 = ws + 524288;                        // 524288 f
    float* wa2  = ws + 1048576;                       // 256 f
    float* cst  = ws + 1048832;                       // 1 f
    unsigned short* h1  = (unsigned short*)(ws + 1048840);   // 524288 us
    unsigned short* h2  = h1 + 2048 * 256;                   // 524288 us
    unsigned short* wtp = h2 + 2048 * 256;                   // 4 x 65536 us

    prep_kernel<<<dim3(288), dim3(256), 0, stream>>>(
        h, Wt, Wtp, Wa, ba, h1, h2, wtp, wa2, cst);
    gemm_kernel<<<dim3(256), dim3(256), 0, stream>>>(h1, h2, wtp, bh, Egt, Egp4);
    attn_kernel<<<dim3(Bn * (Sn / 4)), dim3(1024), 0, stream>>>(
        h, Egt, Egp4, wa2, cst, out, out_attn);
}